// Round 2
// baseline (318.132 us; speedup 1.0000x reference)
//
#include <hip/hip_runtime.h>

#define C2 2.8853900817779268f  // 2*log2(e)
#define DIN 1024
#define HD 512

__device__ __forceinline__ float rcp_fast(float x){ return __builtin_amdgcn_rcpf(x); }
__device__ __forceinline__ float exp2_fast(float x){ return __builtin_amdgcn_exp2f(x); }

// ---------- GEMM split-K: P[(mat*8+slice)][s][j] = sum_{k in slice} x[s][k]*W[j][k]
// 128x128 tile, 256 thr, 8x8 per thread, K-slice=128 staged in 32-k chunks.
// LDS layout: row-major stride 32 floats, float4 slot q stored at q ^ ((row>>3)&7).
__global__ __launch_bounds__(256) void gemm_kernel(
    const float* __restrict__ x, const float* __restrict__ Wh,
    const float* __restrict__ Wm, float* __restrict__ P)
{
    int mat = blockIdx.z >> 3, slice = blockIdx.z & 7;
    const float* W = mat ? Wm : Wh;
    int s0 = blockIdx.y * 128, j0 = blockIdx.x * 128;
    int k0base = slice * 128;
    __shared__ float Xs[128*32];
    __shared__ float Ws[128*32];
    int tid = threadIdx.x;
    int tx = tid & 15, ty = tid >> 4;

    float4 xr[4], wr[4];
    auto load_chunk = [&](int c){
        int k0 = k0base + c*32;
        #pragma unroll
        for (int l = 0; l < 4; l++){
            int row = (tid>>3) + 32*l, q = tid & 7;
            xr[l] = *(const float4*)(x + (s0+row)*DIN + k0 + q*4);
            wr[l] = *(const float4*)(W + (j0+row)*DIN + k0 + q*4);
        }
    };
    auto store_chunk = [&](){
        #pragma unroll
        for (int l = 0; l < 4; l++){
            int row = (tid>>3) + 32*l, q = tid & 7;
            int idx = row*32 + ((q ^ ((row>>3)&7))<<2);
            *(float4*)&Xs[idx] = xr[l];
            *(float4*)&Ws[idx] = wr[l];
        }
    };

    float acc[8][8] = {};
    load_chunk(0);
    for (int c = 0; c < 4; c++){
        __syncthreads();            // previous compute done with LDS
        store_chunk();
        __syncthreads();
        if (c < 3) load_chunk(c+1); // overlap next global load with compute
        #pragma unroll
        for (int qk = 0; qk < 8; qk++){
            float4 a4[8], b4[8];
            #pragma unroll
            for (int i = 0; i < 8; i++)
                a4[i] = *(const float4*)&Xs[(ty*8+i)*32 + ((qk ^ (ty&7))<<2)];
            #pragma unroll
            for (int j = 0; j < 8; j++)
                b4[j] = *(const float4*)&Ws[(tx*8+j)*32 + ((qk ^ (tx&7))<<2)];
            #pragma unroll
            for (int i = 0; i < 8; i++)
                #pragma unroll
                for (int j = 0; j < 8; j++){
                    acc[i][j] = fmaf(a4[i].x, b4[j].x, acc[i][j]);
                    acc[i][j] = fmaf(a4[i].y, b4[j].y, acc[i][j]);
                    acc[i][j] = fmaf(a4[i].z, b4[j].z, acc[i][j]);
                    acc[i][j] = fmaf(a4[i].w, b4[j].w, acc[i][j]);
                }
        }
    }
    float4* P4 = (float4*)P + (size_t)(mat*8 + slice) * 65536;
    #pragma unroll
    for (int i = 0; i < 8; i++){
        int r = s0 + ty*8 + i;
        float4 v0 = {acc[i][0], acc[i][1], acc[i][2], acc[i][3]};
        float4 v1 = {acc[i][4], acc[i][5], acc[i][6], acc[i][7]};
        P4[r*128 + (j0>>2) + tx*2]     = v0;
        P4[r*128 + (j0>>2) + tx*2 + 1] = v1;
    }
}

// ---------- finalize: EH/EM = exp2(C2*(sum of 8 partials + bias))
__global__ __launch_bounds__(256) void finalize_kernel(
    const float* __restrict__ P, const float* __restrict__ bh,
    const float* __restrict__ bm, float* __restrict__ EH, float* __restrict__ EM)
{
    int g = blockIdx.x * 256 + threadIdx.x;   // [0, 131072) float4 units
    int mat = g >> 16;
    int r4 = g & 65535;
    int col4 = r4 & 127;
    const float4* P4 = (const float4*)P + (size_t)mat * 8 * 65536;
    float4 a = P4[r4];
    #pragma unroll
    for (int sl = 1; sl < 8; sl++){
        float4 b = P4[sl*65536 + r4];
        a.x += b.x; a.y += b.y; a.z += b.z; a.w += b.w;
    }
    float4 bias = ((const float4*)(mat ? bm : bh))[col4];
    float4 e = { exp2_fast(C2*(a.x+bias.x)), exp2_fast(C2*(a.y+bias.y)),
                 exp2_fast(C2*(a.z+bias.z)), exp2_fast(C2*(a.w+bias.w)) };
    ((float4*)(mat ? EM : EH))[r4] = e;
}

// ---------- scores partial: Q[ds][h][m] = sum_{d in slice} (-2 w2[d]) * rcp(1+EH[h,d]*EM[m,d])
// 64h x 64m x 64d blocks, 256 thr, 4x4 per thread. Hs row-major (stride 68),
// Ms transposed d-major (stride 68) so m is the contiguous b128 axis.
__global__ __launch_bounds__(256) void scores_kernel(
    const float* __restrict__ EH, const float* __restrict__ EM,
    const float* __restrict__ w2, float* __restrict__ Q)
{
    int m0 = blockIdx.x * 64, h0 = blockIdx.y * 64, d0 = blockIdx.z * 64;
    __shared__ float Hs[64*68];
    __shared__ float Ms[64*68];
    __shared__ float wsS[64];
    int tid = threadIdx.x;
    int tx = tid & 15, ty = tid >> 4;
    #pragma unroll
    for (int l = 0; l < 4; l++){
        int slot = tid + 256*l;
        int row = slot >> 4, q = slot & 15;
        float4 h = *(const float4*)(EH + (h0+row)*HD + d0 + q*4);
        *(float4*)&Hs[row*68 + q*4] = h;
        float4 m = *(const float4*)(EM + (m0+row)*HD + d0 + q*4);
        Ms[(q*4+0)*68 + row] = m.x;
        Ms[(q*4+1)*68 + row] = m.y;
        Ms[(q*4+2)*68 + row] = m.z;
        Ms[(q*4+3)*68 + row] = m.w;
    }
    if (tid < 16){
        float4 w = *(const float4*)(w2 + d0 + tid*4);
        float4 ws = {-2.f*w.x, -2.f*w.y, -2.f*w.z, -2.f*w.w};
        *(float4*)&wsS[tid*4] = ws;
    }
    __syncthreads();
    float acc[4][4] = {};
    #pragma unroll
    for (int it = 0; it < 16; it++){
        int dk = it*4;
        float4 w4 = *(const float4*)&wsS[dk];
        float4 h4[4], mm[4];
        #pragma unroll
        for (int i = 0; i < 4; i++)  h4[i] = *(const float4*)&Hs[(ty*4+i)*68 + dk];
        #pragma unroll
        for (int dd = 0; dd < 4; dd++) mm[dd] = *(const float4*)&Ms[(dk+dd)*68 + tx*4];
        #pragma unroll
        for (int dd = 0; dd < 4; dd++){
            float w  = (dd==0)?w4.x:(dd==1)?w4.y:(dd==2)?w4.z:w4.w;
            float4 mv = mm[dd];
            #pragma unroll
            for (int i = 0; i < 4; i++){
                float eh = (dd==0)?h4[i].x:(dd==1)?h4[i].y:(dd==2)?h4[i].z:h4[i].w;
                acc[i][0] = fmaf(w, rcp_fast(fmaf(eh, mv.x, 1.0f)), acc[i][0]);
                acc[i][1] = fmaf(w, rcp_fast(fmaf(eh, mv.y, 1.0f)), acc[i][1]);
                acc[i][2] = fmaf(w, rcp_fast(fmaf(eh, mv.z, 1.0f)), acc[i][2]);
                acc[i][3] = fmaf(w, rcp_fast(fmaf(eh, mv.w, 1.0f)), acc[i][3]);
            }
        }
    }
    float4* Q4 = (float4*)(Q + (size_t)blockIdx.z * 262144);
    #pragma unroll
    for (int i = 0; i < 4; i++){
        float4 v = {acc[i][0], acc[i][1], acc[i][2], acc[i][3]};
        Q4[(h0 + ty*4 + i)*128 + (m0>>2) + tx] = v;
    }
}

// ---------- combine: out = c0 + sum of 8 d-slice partials, c0 = b2 + sum(w2)
__global__ __launch_bounds__(256) void combine_kernel(
    const float* __restrict__ Q, const float* __restrict__ w2,
    const float* __restrict__ b2, float* __restrict__ out)
{
    int tid = threadIdx.x;
    __shared__ float red[4];
    __shared__ float c0s;
    float s = 0.f;
    if (tid < 128){ float4 v = ((const float4*)w2)[tid]; s = v.x+v.y+v.z+v.w; }
    #pragma unroll
    for (int off = 32; off; off >>= 1) s += __shfl_down(s, off, 64);
    if (tid < 128 && (tid & 63) == 0) red[tid>>6] = s;
    __syncthreads();
    if (tid == 0) c0s = red[0] + red[1] + b2[0];
    __syncthreads();
    float c0 = c0s;
    int g = blockIdx.x * 256 + tid;
    const float4* Q4 = (const float4*)Q;
    float4 a = Q4[g];
    #pragma unroll
    for (int sl = 1; sl < 8; sl++){
        float4 b = Q4[sl*65536 + g];
        a.x += b.x; a.y += b.y; a.z += b.z; a.w += b.w;
    }
    float4 o = {a.x + c0, a.y + c0, a.z + c0, a.w + c0};
    ((float4*)out)[g] = o;
}

extern "C" void kernel_launch(void* const* d_in, const int* in_sizes, int n_in,
                              void* d_out, int out_size, void* d_ws, size_t ws_size,
                              hipStream_t stream) {
    const float* x   = (const float*)d_in[0];   // [1,512,1024]
    const float* Wh  = (const float*)d_in[1];   // [512,1024]
    const float* bh  = (const float*)d_in[2];   // [512]
    const float* Wm  = (const float*)d_in[3];   // [512,1024]
    const float* bm  = (const float*)d_in[4];   // [512]
    const float* w2  = (const float*)d_in[5];   // [512]
    const float* b2  = (const float*)d_in[6];   // [1]
    float* out = (float*)d_out;                 // [512,512]
    (void)in_sizes; (void)n_in; (void)out_size; (void)ws_size;

    float* w  = (float*)d_ws;
    float* EH = w;                         // 262144
    float* EM = w + 262144;                // 262144
    float* P  = w + 524288;                // 16 * 262144 (gemm split-K partials)
    float* Q  = w + 524288 + 16*262144;    // 8 * 262144 (scores d-slice partials)

    gemm_kernel<<<dim3(4, 4, 16), 256, 0, stream>>>(x, Wh, Wm, P);
    finalize_kernel<<<512, 256, 0, stream>>>(P, bh, bm, EH, EM);
    scores_kernel<<<dim3(8, 8, 8), 256, 0, stream>>>(EH, EM, w2, Q);
    combine_kernel<<<256, 256, 0, stream>>>(Q, w2, b2, out);
}

// Round 3
// 132.398 us; speedup vs baseline: 2.4028x; 2.4028x over previous
//
#include <hip/hip_runtime.h>

#define C2 2.8853900817779268f  // 2*log2(e)
#define DIN 1024
#define HD 512

__device__ __forceinline__ float rcp_fast(float x){ return __builtin_amdgcn_rcpf(x); }
__device__ __forceinline__ float exp2_fast(float x){ return __builtin_amdgcn_exp2f(x); }
__device__ __forceinline__ float comp4(const float4& v, int i){
    return i==0 ? v.x : i==1 ? v.y : i==2 ? v.z : v.w;  // i is compile-time under unroll
}

// ---------- GEMM split-K: P[(mat*4+slice)][s][j] = sum_{k in slice} x[s][k]*W[j][k]
// 64x64 tile, 256 thr, 4x4 micro, K-slice=256 staged in 32-k chunks.
// LDS rows stride 36 floats (b128-aligned, bank-walk 4/row -> <=2-way conflicts).
__global__ __launch_bounds__(256, 4) void gemm_kernel(
    const float* __restrict__ x, const float* __restrict__ Wh,
    const float* __restrict__ Wm, float* __restrict__ P)
{
    int mat = blockIdx.z >> 2, slice = blockIdx.z & 3;
    const float* W = mat ? Wm : Wh;
    int s0 = blockIdx.y * 64, j0 = blockIdx.x * 64;
    int k0base = slice * 256;
    __shared__ float Xs[64 * 36];
    __shared__ float Ws[64 * 36];
    int tid = threadIdx.x;
    int tx = tid & 15, ty = tid >> 4;       // tx: j-group (x4), ty: s-group (x4)
    int lrow = tid >> 3, lq = tid & 7;      // staging: 32 rows x 8 float4

    const float* xp = x + (size_t)(s0 + lrow) * DIN + k0base + lq * 4;
    const float* wp = W + (size_t)(j0 + lrow) * DIN + k0base + lq * 4;

    float4 xr0, xr1, wr0, wr1;
    auto load_chunk = [&](int c){
        int off = c * 32;
        xr0 = *(const float4*)(xp + off);
        xr1 = *(const float4*)(xp + off + 32 * DIN);
        wr0 = *(const float4*)(wp + off);
        wr1 = *(const float4*)(wp + off + 32 * DIN);
    };
    auto store_chunk = [&](){
        *(float4*)&Xs[lrow * 36 + lq * 4]        = xr0;
        *(float4*)&Xs[(lrow + 32) * 36 + lq * 4] = xr1;
        *(float4*)&Ws[lrow * 36 + lq * 4]        = wr0;
        *(float4*)&Ws[(lrow + 32) * 36 + lq * 4] = wr1;
    };

    float acc[4][4] = {};
    load_chunk(0);
    for (int c = 0; c < 8; c++){
        __syncthreads();
        store_chunk();
        __syncthreads();
        if (c < 7) load_chunk(c + 1);
        #pragma unroll
        for (int qk = 0; qk < 8; qk++){
            float4 a4[4], b4[4];
            #pragma unroll
            for (int i = 0; i < 4; i++) a4[i] = *(const float4*)&Xs[(ty*4 + i) * 36 + qk * 4];
            #pragma unroll
            for (int j = 0; j < 4; j++) b4[j] = *(const float4*)&Ws[(tx*4 + j) * 36 + qk * 4];
            #pragma unroll
            for (int i = 0; i < 4; i++)
                #pragma unroll
                for (int j = 0; j < 4; j++){
                    acc[i][j] = fmaf(a4[i].x, b4[j].x, acc[i][j]);
                    acc[i][j] = fmaf(a4[i].y, b4[j].y, acc[i][j]);
                    acc[i][j] = fmaf(a4[i].z, b4[j].z, acc[i][j]);
                    acc[i][j] = fmaf(a4[i].w, b4[j].w, acc[i][j]);
                }
        }
    }
    float* Pp = P + (size_t)(mat * 4 + slice) * 262144;
    #pragma unroll
    for (int i = 0; i < 4; i++){
        int r = s0 + ty * 4 + i;
        float4 v = {acc[i][0], acc[i][1], acc[i][2], acc[i][3]};
        *(float4*)&Pp[r * HD + j0 + tx * 4] = v;
    }
}

// ---------- finalize: EH/EM = exp2(C2*(sum of 4 partials + bias))
__global__ __launch_bounds__(256) void finalize_kernel(
    const float* __restrict__ P, const float* __restrict__ bh,
    const float* __restrict__ bm, float* __restrict__ EH, float* __restrict__ EM)
{
    int g = blockIdx.x * 256 + threadIdx.x;   // [0, 131072) float4 units
    int mat = g >> 16;
    int r4 = g & 65535;
    int col4 = r4 & 127;
    const float4* P4 = (const float4*)P + (size_t)mat * 4 * 65536;
    float4 a = P4[r4];
    #pragma unroll
    for (int sl = 1; sl < 4; sl++){
        float4 b = P4[sl * 65536 + r4];
        a.x += b.x; a.y += b.y; a.z += b.z; a.w += b.w;
    }
    float4 bias = ((const float4*)(mat ? bm : bh))[col4];
    float4 e = { exp2_fast(C2 * (a.x + bias.x)), exp2_fast(C2 * (a.y + bias.y)),
                 exp2_fast(C2 * (a.z + bias.z)), exp2_fast(C2 * (a.w + bias.w)) };
    ((float4*)(mat ? EM : EH))[r4] = e;
}

// ---------- scores partial: Q[ds][h][m] = sum_{d in slice} (-2 w2[d]) * rcp(1+EH[h,d]*EM[m,d])
// 64h x 64m x 64d blocks, 256 thr, 4x4 micro. Hs row-major [h][d] stride 68,
// Ms transposed [d][m] stride 68 (m contiguous for b128 reads).
__global__ __launch_bounds__(256, 4) void scores_kernel(
    const float* __restrict__ EH, const float* __restrict__ EM,
    const float* __restrict__ w2, float* __restrict__ Q)
{
    int m0 = blockIdx.x * 64, h0 = blockIdx.y * 64, d0 = blockIdx.z * 64;
    __shared__ float Hs[64 * 68];
    __shared__ float Ms[64 * 68];
    __shared__ float wsS[64];
    int tid = threadIdx.x;
    int tx = tid & 15, ty = tid >> 4;
    #pragma unroll
    for (int l = 0; l < 4; l++){
        int slot = tid + 256 * l;
        int row = slot >> 4, q = slot & 15;
        float4 h = *(const float4*)(EH + (size_t)(h0 + row) * HD + d0 + q * 4);
        *(float4*)&Hs[row * 68 + q * 4] = h;
        float4 m = *(const float4*)(EM + (size_t)(m0 + row) * HD + d0 + q * 4);
        Ms[(q*4 + 0) * 68 + row] = m.x;
        Ms[(q*4 + 1) * 68 + row] = m.y;
        Ms[(q*4 + 2) * 68 + row] = m.z;
        Ms[(q*4 + 3) * 68 + row] = m.w;
    }
    if (tid < 16){
        float4 w = *(const float4*)(w2 + d0 + tid * 4);
        float4 ws = {-2.f * w.x, -2.f * w.y, -2.f * w.z, -2.f * w.w};
        *(float4*)&wsS[tid * 4] = ws;
    }
    __syncthreads();

    float acc[4][4] = {};
    #pragma unroll 2
    for (int it = 0; it < 16; it++){
        int dk = it * 4;
        float4 w4 = *(const float4*)&wsS[dk];
        float4 h0v = *(const float4*)&Hs[(ty*4 + 0) * 68 + dk];
        float4 h1v = *(const float4*)&Hs[(ty*4 + 1) * 68 + dk];
        float4 h2v = *(const float4*)&Hs[(ty*4 + 2) * 68 + dk];
        float4 h3v = *(const float4*)&Hs[(ty*4 + 3) * 68 + dk];
        #pragma unroll
        for (int dd = 0; dd < 4; dd++){
            float4 mv = *(const float4*)&Ms[(dk + dd) * 68 + tx * 4];
            float w = comp4(w4, dd);
            float e0 = comp4(h0v, dd), e1 = comp4(h1v, dd);
            float e2 = comp4(h2v, dd), e3 = comp4(h3v, dd);
            acc[0][0] = fmaf(w, rcp_fast(fmaf(e0, mv.x, 1.f)), acc[0][0]);
            acc[0][1] = fmaf(w, rcp_fast(fmaf(e0, mv.y, 1.f)), acc[0][1]);
            acc[0][2] = fmaf(w, rcp_fast(fmaf(e0, mv.z, 1.f)), acc[0][2]);
            acc[0][3] = fmaf(w, rcp_fast(fmaf(e0, mv.w, 1.f)), acc[0][3]);
            acc[1][0] = fmaf(w, rcp_fast(fmaf(e1, mv.x, 1.f)), acc[1][0]);
            acc[1][1] = fmaf(w, rcp_fast(fmaf(e1, mv.y, 1.f)), acc[1][1]);
            acc[1][2] = fmaf(w, rcp_fast(fmaf(e1, mv.z, 1.f)), acc[1][2]);
            acc[1][3] = fmaf(w, rcp_fast(fmaf(e1, mv.w, 1.f)), acc[1][3]);
            acc[2][0] = fmaf(w, rcp_fast(fmaf(e2, mv.x, 1.f)), acc[2][0]);
            acc[2][1] = fmaf(w, rcp_fast(fmaf(e2, mv.y, 1.f)), acc[2][1]);
            acc[2][2] = fmaf(w, rcp_fast(fmaf(e2, mv.z, 1.f)), acc[2][2]);
            acc[2][3] = fmaf(w, rcp_fast(fmaf(e2, mv.w, 1.f)), acc[2][3]);
            acc[3][0] = fmaf(w, rcp_fast(fmaf(e3, mv.x, 1.f)), acc[3][0]);
            acc[3][1] = fmaf(w, rcp_fast(fmaf(e3, mv.y, 1.f)), acc[3][1]);
            acc[3][2] = fmaf(w, rcp_fast(fmaf(e3, mv.z, 1.f)), acc[3][2]);
            acc[3][3] = fmaf(w, rcp_fast(fmaf(e3, mv.w, 1.f)), acc[3][3]);
        }
    }
    float* Qp = Q + (size_t)blockIdx.z * 262144;
    #pragma unroll
    for (int i = 0; i < 4; i++){
        float4 v = {acc[i][0], acc[i][1], acc[i][2], acc[i][3]};
        *(float4*)&Qp[(h0 + ty*4 + i) * 512 + m0 + tx * 4] = v;
    }
}

// ---------- combine: out = c0 + sum of 8 d-slice partials, c0 = b2 + sum(w2)
__global__ __launch_bounds__(256) void combine_kernel(
    const float* __restrict__ Q, const float* __restrict__ w2,
    const float* __restrict__ b2, float* __restrict__ out)
{
    int tid = threadIdx.x;
    __shared__ float red[4];
    __shared__ float c0s;
    float s = 0.f;
    if (tid < 128){ float4 v = ((const float4*)w2)[tid]; s = v.x + v.y + v.z + v.w; }
    #pragma unroll
    for (int off = 32; off; off >>= 1) s += __shfl_down(s, off, 64);
    if (tid < 128 && (tid & 63) == 0) red[tid >> 6] = s;
    __syncthreads();
    if (tid == 0) c0s = red[0] + red[1] + b2[0];
    __syncthreads();
    float c0 = c0s;
    int g = blockIdx.x * 256 + tid;
    const float4* Q4 = (const float4*)Q;
    float4 a = Q4[g];
    #pragma unroll
    for (int sl = 1; sl < 8; sl++){
        float4 b = Q4[sl * 65536 + g];
        a.x += b.x; a.y += b.y; a.z += b.z; a.w += b.w;
    }
    float4 o = {a.x + c0, a.y + c0, a.z + c0, a.w + c0};
    ((float4*)out)[g] = o;
}

extern "C" void kernel_launch(void* const* d_in, const int* in_sizes, int n_in,
                              void* d_out, int out_size, void* d_ws, size_t ws_size,
                              hipStream_t stream) {
    const float* x   = (const float*)d_in[0];   // [1,512,1024]
    const float* Wh  = (const float*)d_in[1];   // [512,1024]
    const float* bh  = (const float*)d_in[2];   // [512]
    const float* Wm  = (const float*)d_in[3];   // [512,1024]
    const float* bm  = (const float*)d_in[4];   // [512]
    const float* w2  = (const float*)d_in[5];   // [512]
    const float* b2  = (const float*)d_in[6];   // [1]
    float* out = (float*)d_out;                 // [512,512]
    (void)in_sizes; (void)n_in; (void)out_size; (void)ws_size;

    float* w  = (float*)d_ws;
    float* EH = w;                           // 262144
    float* EM = w + 262144;                  // 262144
    float* P  = w + 524288;                  // 8 * 262144 (gemm split-K partials)
    float* Q  = w + 524288 + 8 * 262144;     // 8 * 262144 (scores d-slice partials)

    gemm_kernel<<<dim3(8, 8, 8), 256, 0, stream>>>(x, Wh, Wm, P);
    finalize_kernel<<<512, 256, 0, stream>>>(P, bh, bm, EH, EM);
    scores_kernel<<<dim3(8, 8, 8), 256, 0, stream>>>(EH, EM, w2, Q);
    combine_kernel<<<256, 256, 0, stream>>>(Q, w2, b2, out);
}

// Round 4
// 114.287 us; speedup vs baseline: 2.7836x; 1.1585x over previous
//
#include <hip/hip_runtime.h>

#define C2 2.8853900817779268f  // 2*log2(e)
#define DIN 1024
#define HD 512

__device__ __forceinline__ float rcp_fast(float x){ return __builtin_amdgcn_rcpf(x); }
__device__ __forceinline__ float exp2_fast(float x){ return __builtin_amdgcn_exp2f(x); }
__device__ __forceinline__ float comp4(const float4& v, int i){
    return i==0 ? v.x : i==1 ? v.y : i==2 ? v.z : v.w;  // i compile-time under unroll
}

// ---------- GEMM split-K: P[(mat*8+slice)][s][j] = sum_{k in slice} x[s][k]*W[j][k]
// 64x64 tile, 256 thr, 4x4 micro, K-slice=128 staged in 32-k chunks.
// LDS: row stride 32 floats, float4 slot q stored at q ^ ((row>>2)&7)  ->
//   b-frag reads: 8 bank groups x 2 addrs = free; a-frag: 4 groups x 1 = free;
//   staging stores: uniform 8 lanes/group = b128 structural minimum.
__global__ __launch_bounds__(256, 4) void gemm_kernel(
    const float* __restrict__ x, const float* __restrict__ Wh,
    const float* __restrict__ Wm, float* __restrict__ P)
{
    int mat = blockIdx.z >> 3, slice = blockIdx.z & 7;
    const float* W = mat ? Wm : Wh;
    int s0 = blockIdx.y * 64, j0 = blockIdx.x * 64;
    int k0base = slice * 128;
    __shared__ float Xs[64 * 32];
    __shared__ float Ws[64 * 32];
    int tid = threadIdx.x;
    int tx = tid & 15, ty = tid >> 4;       // tx: j-group (x4), ty: s-group (x4)
    int lrow = tid >> 3, lq = tid & 7;      // staging: 32 rows x 8 float4

    const float* xp = x + (size_t)(s0 + lrow) * DIN + k0base + lq * 4;
    const float* wp = W + (size_t)(j0 + lrow) * DIN + k0base + lq * 4;

    // swizzled LDS float-index for (row, float4-slot q)
    auto sidx = [](int row, int q){ return row * 32 + ((q ^ ((row >> 2) & 7)) << 2); };

    float4 xr0, xr1, wr0, wr1;
    auto load_chunk = [&](int c){
        int off = c * 32;
        xr0 = *(const float4*)(xp + off);
        xr1 = *(const float4*)(xp + off + 32 * DIN);
        wr0 = *(const float4*)(wp + off);
        wr1 = *(const float4*)(wp + off + 32 * DIN);
    };
    auto store_chunk = [&](){
        *(float4*)&Xs[sidx(lrow, lq)]      = xr0;
        *(float4*)&Xs[sidx(lrow + 32, lq)] = xr1;
        *(float4*)&Ws[sidx(lrow, lq)]      = wr0;
        *(float4*)&Ws[sidx(lrow + 32, lq)] = wr1;
    };

    float acc[4][4] = {};
    load_chunk(0);
    for (int c = 0; c < 4; c++){
        __syncthreads();
        store_chunk();
        __syncthreads();
        if (c < 3) load_chunk(c + 1);
        #pragma unroll
        for (int qk = 0; qk < 8; qk++){
            float4 a4[4], b4[4];
            #pragma unroll
            for (int i = 0; i < 4; i++)
                a4[i] = *(const float4*)&Xs[(ty*4 + i) * 32 + ((qk ^ (ty & 7)) << 2)];
            #pragma unroll
            for (int j = 0; j < 4; j++)
                b4[j] = *(const float4*)&Ws[(tx*4 + j) * 32 + ((qk ^ (tx & 7)) << 2)];
            #pragma unroll
            for (int i = 0; i < 4; i++)
                #pragma unroll
                for (int j = 0; j < 4; j++){
                    acc[i][j] = fmaf(a4[i].x, b4[j].x, acc[i][j]);
                    acc[i][j] = fmaf(a4[i].y, b4[j].y, acc[i][j]);
                    acc[i][j] = fmaf(a4[i].z, b4[j].z, acc[i][j]);
                    acc[i][j] = fmaf(a4[i].w, b4[j].w, acc[i][j]);
                }
        }
    }
    float* Pp = P + (size_t)(mat * 8 + slice) * 262144;
    #pragma unroll
    for (int i = 0; i < 4; i++){
        int r = s0 + ty * 4 + i;
        float4 v = {acc[i][0], acc[i][1], acc[i][2], acc[i][3]};
        *(float4*)&Pp[r * HD + j0 + tx * 4] = v;
    }
}

// ---------- finalize: EH/EM = exp2(C2*(sum of 8 partials + bias))
__global__ __launch_bounds__(256) void finalize_kernel(
    const float* __restrict__ P, const float* __restrict__ bh,
    const float* __restrict__ bm, float* __restrict__ EH, float* __restrict__ EM)
{
    int g = blockIdx.x * 256 + threadIdx.x;   // [0, 131072) float4 units
    int mat = g >> 16;
    int r4 = g & 65535;
    int col4 = r4 & 127;
    const float4* P4 = (const float4*)P + (size_t)mat * 8 * 65536;
    float4 a = P4[r4];
    #pragma unroll
    for (int sl = 1; sl < 8; sl++){
        float4 b = P4[sl * 65536 + r4];
        a.x += b.x; a.y += b.y; a.z += b.z; a.w += b.w;
    }
    float4 bias = ((const float4*)(mat ? bm : bh))[col4];
    float4 e = { exp2_fast(C2 * (a.x + bias.x)), exp2_fast(C2 * (a.y + bias.y)),
                 exp2_fast(C2 * (a.z + bias.z)), exp2_fast(C2 * (a.w + bias.w)) };
    ((float4*)(mat ? EM : EH))[r4] = e;
}

// ---------- scores partial: Q[ds][h][m] = sum_{d in slice} (-2 w2[d]) * rcp(1+EH[h,d]*EM[m,d])
// 32h x 64m x 64d blocks (1024 blocks, 4/CU), 256 thr, 2x4 micro.
// Hs row-major [h][d] stride 68; Ms transposed [d][m] stride 68.
__global__ __launch_bounds__(256, 4) void scores_kernel(
    const float* __restrict__ EH, const float* __restrict__ EM,
    const float* __restrict__ w2, float* __restrict__ Q)
{
    int m0 = blockIdx.x * 64, h0 = blockIdx.y * 32, d0 = blockIdx.z * 64;
    __shared__ float Hs[32 * 68];
    __shared__ float Ms[64 * 68];
    __shared__ float wsS[64];
    int tid = threadIdx.x;
    int tx = tid & 15, ty = tid >> 4;   // tx: m-group (x4), ty: h-group (x2)
    #pragma unroll
    for (int l = 0; l < 2; l++){        // Hs: 32 rows x 16 float4
        int slot = tid + 256 * l;
        int row = slot >> 4, q = slot & 15;
        float4 h = *(const float4*)(EH + (size_t)(h0 + row) * HD + d0 + q * 4);
        *(float4*)&Hs[row * 68 + q * 4] = h;
    }
    #pragma unroll
    for (int l = 0; l < 4; l++){        // Ms: 64 m-rows x 16 float4, transposed scatter
        int slot = tid + 256 * l;
        int m = slot >> 4, q = slot & 15;
        float4 v = *(const float4*)(EM + (size_t)(m0 + m) * HD + d0 + q * 4);
        Ms[(q*4 + 0) * 68 + m] = v.x;
        Ms[(q*4 + 1) * 68 + m] = v.y;
        Ms[(q*4 + 2) * 68 + m] = v.z;
        Ms[(q*4 + 3) * 68 + m] = v.w;
    }
    if (tid < 16){
        float4 w = *(const float4*)(w2 + d0 + tid * 4);
        float4 ws = {-2.f * w.x, -2.f * w.y, -2.f * w.z, -2.f * w.w};
        *(float4*)&wsS[tid * 4] = ws;
    }
    __syncthreads();

    float acc[2][4] = {};
    #pragma unroll 2
    for (int it = 0; it < 16; it++){
        int dk = it * 4;
        float4 w4 = *(const float4*)&wsS[dk];
        float4 hA = *(const float4*)&Hs[(ty*2 + 0) * 68 + dk];
        float4 hB = *(const float4*)&Hs[(ty*2 + 1) * 68 + dk];
        #pragma unroll
        for (int dd = 0; dd < 4; dd++){
            float4 mv = *(const float4*)&Ms[(dk + dd) * 68 + tx * 4];
            float w = comp4(w4, dd);
            float e0 = comp4(hA, dd), e1 = comp4(hB, dd);
            acc[0][0] = fmaf(w, rcp_fast(fmaf(e0, mv.x, 1.f)), acc[0][0]);
            acc[0][1] = fmaf(w, rcp_fast(fmaf(e0, mv.y, 1.f)), acc[0][1]);
            acc[0][2] = fmaf(w, rcp_fast(fmaf(e0, mv.z, 1.f)), acc[0][2]);
            acc[0][3] = fmaf(w, rcp_fast(fmaf(e0, mv.w, 1.f)), acc[0][3]);
            acc[1][0] = fmaf(w, rcp_fast(fmaf(e1, mv.x, 1.f)), acc[1][0]);
            acc[1][1] = fmaf(w, rcp_fast(fmaf(e1, mv.y, 1.f)), acc[1][1]);
            acc[1][2] = fmaf(w, rcp_fast(fmaf(e1, mv.z, 1.f)), acc[1][2]);
            acc[1][3] = fmaf(w, rcp_fast(fmaf(e1, mv.w, 1.f)), acc[1][3]);
        }
    }
    float* Qp = Q + (size_t)blockIdx.z * 262144;
    #pragma unroll
    for (int i = 0; i < 2; i++){
        float4 v = {acc[i][0], acc[i][1], acc[i][2], acc[i][3]};
        *(float4*)&Qp[(h0 + ty*2 + i) * 512 + m0 + tx * 4] = v;
    }
}

// ---------- combine: out = c0 + sum of 8 d-slice partials, c0 = b2 + sum(w2)
__global__ __launch_bounds__(256) void combine_kernel(
    const float* __restrict__ Q, const float* __restrict__ w2,
    const float* __restrict__ b2, float* __restrict__ out)
{
    int tid = threadIdx.x;
    __shared__ float red[4];
    __shared__ float c0s;
    float s = 0.f;
    if (tid < 128){ float4 v = ((const float4*)w2)[tid]; s = v.x + v.y + v.z + v.w; }
    #pragma unroll
    for (int off = 32; off; off >>= 1) s += __shfl_down(s, off, 64);
    if (tid < 128 && (tid & 63) == 0) red[tid >> 6] = s;
    __syncthreads();
    if (tid == 0) c0s = red[0] + red[1] + b2[0];
    __syncthreads();
    float c0 = c0s;
    int g = blockIdx.x * 256 + tid;
    const float4* Q4 = (const float4*)Q;
    float4 a = Q4[g];
    #pragma unroll
    for (int sl = 1; sl < 8; sl++){
        float4 b = Q4[sl * 65536 + g];
        a.x += b.x; a.y += b.y; a.z += b.z; a.w += b.w;
    }
    float4 o = {a.x + c0, a.y + c0, a.z + c0, a.w + c0};
    ((float4*)out)[g] = o;
}

extern "C" void kernel_launch(void* const* d_in, const int* in_sizes, int n_in,
                              void* d_out, int out_size, void* d_ws, size_t ws_size,
                              hipStream_t stream) {
    const float* x   = (const float*)d_in[0];   // [1,512,1024]
    const float* Wh  = (const float*)d_in[1];   // [512,1024]
    const float* bh  = (const float*)d_in[2];   // [512]
    const float* Wm  = (const float*)d_in[3];   // [512,1024]
    const float* bm  = (const float*)d_in[4];   // [512]
    const float* w2  = (const float*)d_in[5];   // [512]
    const float* b2  = (const float*)d_in[6];   // [1]
    float* out = (float*)d_out;                 // [512,512]
    (void)in_sizes; (void)n_in; (void)out_size; (void)ws_size;

    float* w  = (float*)d_ws;
    float* EH = w;                            // 262144
    float* EM = w + 262144;                   // 262144
    float* P  = w + 524288;                   // 16 * 262144 (gemm split-K partials)
    float* Q  = w + 524288 + 16 * 262144;     // 8 * 262144 (scores d-slice partials)

    gemm_kernel<<<dim3(8, 8, 16), 256, 0, stream>>>(x, Wh, Wm, P);
    finalize_kernel<<<512, 256, 0, stream>>>(P, bh, bm, EH, EM);
    scores_kernel<<<dim3(8, 16, 8), 256, 0, stream>>>(EH, EM, w2, Q);
    combine_kernel<<<256, 256, 0, stream>>>(Q, w2, b2, out);
}

// Round 5
// 109.050 us; speedup vs baseline: 2.9173x; 1.0480x over previous
//
#include <hip/hip_runtime.h>

#define C2 2.8853900817779268f  // 2*log2(e)
#define DIN 1024
#define HD 512

typedef short short8 __attribute__((ext_vector_type(8)));   // 8 bf16 (4 VGPRs)
typedef float floatx4 __attribute__((ext_vector_type(4)));  // MFMA acc

__device__ __forceinline__ float rcp_fast(float x){ return __builtin_amdgcn_rcpf(x); }
__device__ __forceinline__ float exp2_fast(float x){ return __builtin_amdgcn_exp2f(x); }
__device__ __forceinline__ float comp4(const float4& v, int i){
    return i==0 ? v.x : i==1 ? v.y : i==2 ? v.z : v.w;  // i compile-time under unroll
}
__device__ __forceinline__ unsigned short f2bf(float f){   // RNE fp32->bf16
    union{float f; unsigned int u;} v; v.f = f;
    unsigned int u = v.u;
    return (unsigned short)((u + 0x7FFFu + ((u >> 16) & 1u)) >> 16);
}

// ---------- convert: x, Wh, Wm (fp32) -> bf16 buffers ----------
__global__ __launch_bounds__(256) void convert_kernel(
    const float* __restrict__ x, const float* __restrict__ Wh,
    const float* __restrict__ Wm, unsigned short* __restrict__ xb,
    unsigned short* __restrict__ whb, unsigned short* __restrict__ wmb)
{
    int r = blockIdx.z;
    const float* s = r == 0 ? x : r == 1 ? Wh : Wm;
    unsigned short* d = r == 0 ? xb : r == 1 ? whb : wmb;
    int i = (blockIdx.x * 256 + threadIdx.x) * 4;   // 512 blocks x 256 thr x 4 = 524288
    float4 v = *(const float4*)(s + i);
    ushort4 o = { f2bf(v.x), f2bf(v.y), f2bf(v.z), f2bf(v.w) };
    *(ushort4*)(d + i) = o;
}

// ---------- MFMA gemm + fused exp2 epilogue ----------
// C[s,j] = sum_k x[s,k] * W[j,k];  EH/EM[s,j] = exp2(C2*(C+bias[j]))
// One 16x16 C tile per wave via mfma_f32_16x16x32_bf16, K=1024 in 32-steps.
// A frag: row m=lane&15, k=quad*8+j (one dwordx4).  B frag: col n=lane&15 (W row-major = B^T). 
// C/D: col=lane&15, row=quad*4+reg  [m89/m120-verified layouts]
__global__ __launch_bounds__(256) void mfma_gemm_kernel(
    const unsigned short* __restrict__ xb, const unsigned short* __restrict__ whb,
    const unsigned short* __restrict__ wmb, const float* __restrict__ bh,
    const float* __restrict__ bm, float* __restrict__ EH, float* __restrict__ EM)
{
    int mat = blockIdx.z;
    const unsigned short* B = mat ? wmb : whb;
    const float* bias = mat ? bm : bh;
    float* O = mat ? EM : EH;
    int j0 = blockIdx.x * 32, s0 = blockIdx.y * 32;
    int wave = threadIdx.x >> 6, lane = threadIdx.x & 63;
    int sw = (wave & 1) * 16, jw = (wave >> 1) * 16;
    int m = lane & 15, quad = lane >> 4;

    const unsigned short* ap = xb + (size_t)(s0 + sw + m) * DIN + quad * 8;
    const unsigned short* bp = B  + (size_t)(j0 + jw + m) * DIN + quad * 8;

    floatx4 acc = {0.f, 0.f, 0.f, 0.f};
    #pragma unroll 8
    for (int k = 0; k < DIN; k += 32){
        short8 af = *(const short8*)(ap + k);
        short8 bf = *(const short8*)(bp + k);
        acc = __builtin_amdgcn_mfma_f32_16x16x32_bf16(af, bf, acc, 0, 0, 0);
    }
    int col = j0 + jw + m;
    float bv = bias[col];
    #pragma unroll
    for (int i = 0; i < 4; i++){
        int row = s0 + sw + quad * 4 + i;
        O[(size_t)row * HD + col] = exp2_fast(C2 * (acc[i] + bv));
    }
}

// ---------- scores partial: Q[ds][h][m] = sum_{d in slice} (-2 w2[d]) * rcp(1+EH[h,d]*EM[m,d])
// 32h x 64m x 64d blocks (1024 blocks, 4/CU), 256 thr, 2x4 micro.
// Hs row-major [h][d] stride 68; Ms transposed [d][m] stride 68.
__global__ __launch_bounds__(256, 4) void scores_kernel(
    const float* __restrict__ EH, const float* __restrict__ EM,
    const float* __restrict__ w2, float* __restrict__ Q)
{
    int m0 = blockIdx.x * 64, h0 = blockIdx.y * 32, d0 = blockIdx.z * 64;
    __shared__ float Hs[32 * 68];
    __shared__ float Ms[64 * 68];
    __shared__ float wsS[64];
    int tid = threadIdx.x;
    int tx = tid & 15, ty = tid >> 4;   // tx: m-group (x4), ty: h-group (x2)
    #pragma unroll
    for (int l = 0; l < 2; l++){        // Hs: 32 rows x 16 float4
        int slot = tid + 256 * l;
        int row = slot >> 4, q = slot & 15;
        float4 h = *(const float4*)(EH + (size_t)(h0 + row) * HD + d0 + q * 4);
        *(float4*)&Hs[row * 68 + q * 4] = h;
    }
    #pragma unroll
    for (int l = 0; l < 4; l++){        // Ms: 64 m-rows x 16 float4, transposed scatter
        int slot = tid + 256 * l;
        int mm = slot >> 4, q = slot & 15;
        float4 v = *(const float4*)(EM + (size_t)(m0 + mm) * HD + d0 + q * 4);
        Ms[(q*4 + 0) * 68 + mm] = v.x;
        Ms[(q*4 + 1) * 68 + mm] = v.y;
        Ms[(q*4 + 2) * 68 + mm] = v.z;
        Ms[(q*4 + 3) * 68 + mm] = v.w;
    }
    if (tid < 16){
        float4 w = *(const float4*)(w2 + d0 + tid * 4);
        float4 ws = {-2.f * w.x, -2.f * w.y, -2.f * w.z, -2.f * w.w};
        *(float4*)&wsS[tid * 4] = ws;
    }
    __syncthreads();

    float acc[2][4] = {};
    #pragma unroll 2
    for (int it = 0; it < 16; it++){
        int dk = it * 4;
        float4 w4 = *(const float4*)&wsS[dk];
        float4 hA = *(const float4*)&Hs[(ty*2 + 0) * 68 + dk];
        float4 hB = *(const float4*)&Hs[(ty*2 + 1) * 68 + dk];
        #pragma unroll
        for (int dd = 0; dd < 4; dd++){
            float4 mv = *(const float4*)&Ms[(dk + dd) * 68 + tx * 4];
            float w = comp4(w4, dd);
            float e0 = comp4(hA, dd), e1 = comp4(hB, dd);
            acc[0][0] = fmaf(w, rcp_fast(fmaf(e0, mv.x, 1.f)), acc[0][0]);
            acc[0][1] = fmaf(w, rcp_fast(fmaf(e0, mv.y, 1.f)), acc[0][1]);
            acc[0][2] = fmaf(w, rcp_fast(fmaf(e0, mv.z, 1.f)), acc[0][2]);
            acc[0][3] = fmaf(w, rcp_fast(fmaf(e0, mv.w, 1.f)), acc[0][3]);
            acc[1][0] = fmaf(w, rcp_fast(fmaf(e1, mv.x, 1.f)), acc[1][0]);
            acc[1][1] = fmaf(w, rcp_fast(fmaf(e1, mv.y, 1.f)), acc[1][1]);
            acc[1][2] = fmaf(w, rcp_fast(fmaf(e1, mv.z, 1.f)), acc[1][2]);
            acc[1][3] = fmaf(w, rcp_fast(fmaf(e1, mv.w, 1.f)), acc[1][3]);
        }
    }
    float* Qp = Q + (size_t)blockIdx.z * 262144;
    #pragma unroll
    for (int i = 0; i < 2; i++){
        float4 v = {acc[i][0], acc[i][1], acc[i][2], acc[i][3]};
        *(float4*)&Qp[(h0 + ty*2 + i) * 512 + m0 + tx * 4] = v;
    }
}

// ---------- combine: out = c0 + sum of 8 d-slice partials, c0 = b2 + sum(w2)
__global__ __launch_bounds__(256) void combine_kernel(
    const float* __restrict__ Q, const float* __restrict__ w2,
    const float* __restrict__ b2, float* __restrict__ out)
{
    int tid = threadIdx.x;
    __shared__ float red[4];
    __shared__ float c0s;
    float s = 0.f;
    if (tid < 128){ float4 v = ((const float4*)w2)[tid]; s = v.x + v.y + v.z + v.w; }
    #pragma unroll
    for (int off = 32; off; off >>= 1) s += __shfl_down(s, off, 64);
    if (tid < 128 && (tid & 63) == 0) red[tid >> 6] = s;
    __syncthreads();
    if (tid == 0) c0s = red[0] + red[1] + b2[0];
    __syncthreads();
    float c0 = c0s;
    int g = blockIdx.x * 256 + tid;
    const float4* Q4 = (const float4*)Q;
    float4 a = Q4[g];
    #pragma unroll
    for (int sl = 1; sl < 8; sl++){
        float4 b = Q4[sl * 65536 + g];
        a.x += b.x; a.y += b.y; a.z += b.z; a.w += b.w;
    }
    float4 o = {a.x + c0, a.y + c0, a.z + c0, a.w + c0};
    ((float4*)out)[g] = o;
}

extern "C" void kernel_launch(void* const* d_in, const int* in_sizes, int n_in,
                              void* d_out, int out_size, void* d_ws, size_t ws_size,
                              hipStream_t stream) {
    const float* x   = (const float*)d_in[0];   // [1,512,1024]
    const float* Wh  = (const float*)d_in[1];   // [512,1024]
    const float* bh  = (const float*)d_in[2];   // [512]
    const float* Wm  = (const float*)d_in[3];   // [512,1024]
    const float* bm  = (const float*)d_in[4];   // [512]
    const float* w2  = (const float*)d_in[5];   // [512]
    const float* b2  = (const float*)d_in[6];   // [1]
    float* out = (float*)d_out;                 // [512,512]
    (void)in_sizes; (void)n_in; (void)out_size; (void)ws_size;

    float* w = (float*)d_ws;
    unsigned short* xb  = (unsigned short*)(w);            // 524288 bf16 = 262144 f
    unsigned short* whb = (unsigned short*)(w + 262144);   // 262144 f
    unsigned short* wmb = (unsigned short*)(w + 524288);   // 262144 f
    float* EH = w + 786432;                                // 262144
    float* EM = w + 1048576;                               // 262144
    float* Q  = w + 1310720;                               // 8 * 262144

    convert_kernel<<<dim3(512, 1, 3), 256, 0, stream>>>(x, Wh, Wm, xb, whb, wmb);
    mfma_gemm_kernel<<<dim3(16, 16, 2), 256, 0, stream>>>(xb, whb, wmb, bh, bm, EH, EM);
    scores_kernel<<<dim3(8, 16, 8), 256, 0, stream>>>(EH, EM, w2, Q);
    combine_kernel<<<256, 256, 0, stream>>>(Q, w2, b2, out);
}